// Round 2
// baseline (1774.676 us; speedup 1.0000x reference)
//
#include <hip/hip_runtime.h>

#define BB 16
#define TT 750
#define FF 4096
#define CC 20
#define K_ACT 93
#define K_BKG 93
#define NROWS (BB * TT)   // 12000

typedef float f32x4 __attribute__((ext_vector_type(4)));  // NT-builtin-compatible

// ---------------------------------------------------------------------------
// K1: fused features-copy + masked GEMM (cas logits) + ||x||^2 (fp64)
// v2: 2 rows/block (6000 blocks), 256 threads, forced 4 waves/SIMD occupancy,
// shfl-butterfly reduction (no LDS bank conflicts), NT hints on mask/features.
// ---------------------------------------------------------------------------
__global__ __launch_bounds__(256, 4) void k_main(
    const float* __restrict__ x, const float* __restrict__ w,
    const float* __restrict__ mask, float* __restrict__ features,
    float* __restrict__ cas_ws, double* __restrict__ mag2_ws)
{
    const int tid = threadIdx.x;
    const int row0 = blockIdx.x * 2;

    float acc[2][CC];
#pragma unroll
    for (int r = 0; r < 2; ++r)
#pragma unroll
        for (int c = 0; c < CC; ++c) acc[r][c] = 0.f;
    double mg[2] = {0.0, 0.0};

#pragma unroll
    for (int k = 0; k < 2; ++k) {
        const int fb = k * 2048 + tid * 8;
        float mk[2][8];
#pragma unroll
        for (int r = 0; r < 2; ++r) {
            const size_t off = (size_t)(row0 + r) * FF + fb;
            const f32x4 a0 = *(const f32x4*)(x + off);
            const f32x4 a1 = *(const f32x4*)(x + off + 4);
            const f32x4 m0 = __builtin_nontemporal_load((const f32x4*)(mask + off));
            const f32x4 m1 = __builtin_nontemporal_load((const f32x4*)(mask + off + 4));
            __builtin_nontemporal_store(a0, (f32x4*)(features + off));      // pass-through (bit-exact)
            __builtin_nontemporal_store(a1, (f32x4*)(features + off + 4));
            mk[r][0] = a0[0] * m0[0]; mk[r][1] = a0[1] * m0[1];
            mk[r][2] = a0[2] * m0[2]; mk[r][3] = a0[3] * m0[3];
            mk[r][4] = a1[0] * m1[0]; mk[r][5] = a1[1] * m1[1];
            mk[r][6] = a1[2] * m1[2]; mk[r][7] = a1[3] * m1[3];
            mg[r] = fma((double)a0[0], (double)a0[0], mg[r]);
            mg[r] = fma((double)a0[1], (double)a0[1], mg[r]);
            mg[r] = fma((double)a0[2], (double)a0[2], mg[r]);
            mg[r] = fma((double)a0[3], (double)a0[3], mg[r]);
            mg[r] = fma((double)a1[0], (double)a1[0], mg[r]);
            mg[r] = fma((double)a1[1], (double)a1[1], mg[r]);
            mg[r] = fma((double)a1[2], (double)a1[2], mg[r]);
            mg[r] = fma((double)a1[3], (double)a1[3], mg[r]);
        }
#pragma unroll
        for (int c = 0; c < CC; ++c) {
            const f32x4 w0 = *(const f32x4*)(w + (size_t)c * FF + fb);
            const f32x4 w1 = *(const f32x4*)(w + (size_t)c * FF + fb + 4);
            float wf[8] = {w0[0], w0[1], w0[2], w0[3], w1[0], w1[1], w1[2], w1[3]};
#pragma unroll
            for (int r = 0; r < 2; ++r)
#pragma unroll
                for (int j = 0; j < 8; ++j)
                    acc[r][c] = fmaf(mk[r][j], wf[j], acc[r][c]);
        }
    }

    // reduction: 64-lane butterfly (all lanes end with wave total), then
    // lane 0 of each wave deposits 20 partials + mag into tiny LDS (static
    // indexing only — never index a register array with a runtime lane id)
    __shared__ float redw[2][4][CC];
    __shared__ double redd[2][4];
    const int wv = tid >> 6;
    const int ln = tid & 63;

#pragma unroll
    for (int r = 0; r < 2; ++r) {
#pragma unroll
        for (int c = 0; c < CC; ++c) {
            float v = acc[r][c];
#pragma unroll
            for (int off = 1; off < 64; off <<= 1) v += __shfl_xor(v, off, 64);
            acc[r][c] = v;
        }
        double d = mg[r];
#pragma unroll
        for (int off = 1; off < 64; off <<= 1) d += __shfl_xor(d, off, 64);
        if (ln == 0) {
#pragma unroll
            for (int c = 0; c < CC; ++c) redw[r][wv][c] = acc[r][c];
            redd[r][wv] = d;
        }
    }
    __syncthreads();
    if (tid < 2 * CC) {
        const int r = tid / CC, c = tid % CC;
        cas_ws[(size_t)(row0 + r) * CC + c] =
            (redw[r][0][c] + redw[r][1][c]) + (redw[r][2][c] + redw[r][3][c]);
    } else if (tid < 2 * CC + 2) {
        const int r = tid - 2 * CC;
        mag2_ws[row0 + r] = (redd[r][0] + redd[r][1]) + (redd[r][2] + redd[r][3]);
    }
}

// ---------------------------------------------------------------------------
// K2 (merged): blocks [0,48) = exact top-k index selection (unchanged logic)
//              blocks [48,368) = mean of top-93 of each cas column
// Both depend only on k_main outputs; cassm is NOT here (it clobbers the
// logits in place that colmean reads).
// ---------------------------------------------------------------------------
__global__ __launch_bounds__(256) void k_mid(
    const double* __restrict__ mag2_ws, const float* __restrict__ smask,
    const float* __restrict__ cas_ws,
    int* __restrict__ idxA, int* __restrict__ idxB, float* __restrict__ meansA)
{
    const int bid = blockIdx.x;
    const int tid = threadIdx.x;

    if (bid < BB * 3) {
        // ---- top-k body (stable desc, lower index first; fp64 keys) ----
        const int b = bid / 3;
        const int chunk = bid % 3;

        __shared__ double m2[TT];
        __shared__ unsigned char alive[TT];
        __shared__ double mred[256];

        for (int t = tid; t < TT; t += 256) {
            m2[t] = mag2_ws[b * TT + t];
            alive[t] = (smask[b * TT + t] != 0.f);
        }
        __syncthreads();
        double lm = 0.0;
        for (int t = tid; t < TT; t += 256) lm = fmax(lm, m2[t]);
        mred[tid] = lm;
        __syncthreads();
        for (int s = 128; s > 0; s >>= 1) {
            if (tid < s) mred[tid] = fmax(mred[tid], mred[tid + s]);
            __syncthreads();
        }
        const double mx = mred[0];

        const int t = chunk * 250 + tid;
        if (tid < 250 && t < TT && alive[t]) {
            const double v = m2[t];
            const bool posB = v < mx;  // bkg key (mx - v)*s is positive
            int rA = 0, rB = 0;
            for (int u = 0; u < TT; ++u) {
                if (!alive[u]) continue;
                const double wv = m2[u];
                if (wv > v || (wv == v && u < t)) ++rA;
                if (posB && wv < mx && (wv < v || (wv == v && u < t))) ++rB;
            }
            if (rA < K_ACT) idxA[b * K_ACT + rA] = t;
            if (posB && rB < K_BKG) idxB[b * K_BKG + rB] = t;
        }
    } else {
        // ---- colmean body ----
        const int cb = bid - BB * 3;
        const int b = cb / CC;
        const int c = cb % CC;

        __shared__ float col[TT];
        __shared__ float pred[256];

        for (int t = tid; t < TT; t += 256) col[t] = cas_ws[(size_t)(b * TT + t) * CC + c];
        __syncthreads();

        float loc = 0.f;
        for (int t = tid; t < TT; t += 256) {
            const float v = col[t];
            int cnt = 0;
            for (int u = 0; u < TT; ++u) {
                const float wv = col[u];
                cnt += (wv > v) || (wv == v && u < t);
            }
            if (cnt < K_ACT) loc += v;
        }
        pred[tid] = loc;
        __syncthreads();
        for (int s = 128; s > 0; s >>= 1) {
            if (tid < s) pred[tid] += pred[tid + s];
            __syncthreads();
        }
        if (tid == 0) meansA[b * CC + c] = pred[0] / (float)K_ACT;
    }
}

// ---------------------------------------------------------------------------
// K3 (merged): blocks [0,2976) = gather feat_act / feat_bkg rows
//              blocks [2976,2992) = score_bkg mean + both softmaxes
// (scores reads raw logits; cassm runs after this kernel)
// ---------------------------------------------------------------------------
__global__ __launch_bounds__(256) void k_fin(
    const float* __restrict__ x, const float* __restrict__ cas_ws,
    const float* __restrict__ meansA,
    const int* __restrict__ idxA, const int* __restrict__ idxB,
    float* __restrict__ featA, float* __restrict__ featB,
    float* __restrict__ score_act, float* __restrict__ score_bkg)
{
    int g = blockIdx.x;
    const int tid = threadIdx.x;
    const int nA = BB * K_ACT;

    if (g < 2 * nA) {
        // ---- gather body ----
        const bool isB = (g >= nA);
        if (isB) g -= nA;
        const int b = g / K_ACT;
        int t = (isB ? idxB : idxA)[g];
        t = min(max(t, 0), TT - 1);
        const f32x4* src = (const f32x4*)(x + (size_t)(b * TT + t) * FF);
        f32x4* dst = (f32x4*)((isB ? featB : featA) + (size_t)g * FF);
        for (int i = tid; i < FF / 4; i += 256) dst[i] = src[i];
    } else {
        // ---- scores body ----
        const int b = g - 2 * nA;
        __shared__ float mB[CC];

        if (tid < CC) {
            float s = 0.f;
            for (int j = 0; j < K_BKG; ++j) {
                int t = idxB[b * K_BKG + j];
                t = min(max(t, 0), TT - 1);
                s += cas_ws[(size_t)(b * TT + t) * CC + tid];
            }
            mB[tid] = s / (float)K_BKG;
        }
        __syncthreads();
        if (tid == 0) {
            float va[CC], vb[CC];
            float ma = -1e30f, sa = 0.f;
            for (int c = 0; c < CC; ++c) { va[c] = meansA[b * CC + c]; ma = fmaxf(ma, va[c]); }
            for (int c = 0; c < CC; ++c) { va[c] = expf(va[c] - ma); sa += va[c]; }
            for (int c = 0; c < CC; ++c) score_act[b * CC + c] = va[c] / sa;
            float mb = -1e30f, sb = 0.f;
            for (int c = 0; c < CC; ++c) { vb[c] = mB[c]; mb = fmaxf(mb, vb[c]); }
            for (int c = 0; c < CC; ++c) { vb[c] = expf(vb[c] - mb); sb += vb[c]; }
            for (int c = 0; c < CC; ++c) score_bkg[b * CC + c] = vb[c] / sb;
        }
    }
}

// ---------------------------------------------------------------------------
// K4: cas_softmax over C per (b,t) row — IN PLACE on the cas logits (must be
// the last reader/writer of the logits region)
// ---------------------------------------------------------------------------
__global__ __launch_bounds__(256) void k_cassm(float* __restrict__ cas)
{
    const int row = blockIdx.x * 256 + threadIdx.x;
    if (row >= NROWS) return;
    f32x4* p = (f32x4*)(cas + (size_t)row * CC);
    float v[CC];
#pragma unroll
    for (int i = 0; i < 5; ++i) {
        const f32x4 q = p[i];
        v[4 * i] = q[0]; v[4 * i + 1] = q[1]; v[4 * i + 2] = q[2]; v[4 * i + 3] = q[3];
    }
    float m = v[0];
#pragma unroll
    for (int c = 1; c < CC; ++c) m = fmaxf(m, v[c]);
    float s = 0.f;
#pragma unroll
    for (int c = 0; c < CC; ++c) { v[c] = expf(v[c] - m); s += v[c]; }
    const float inv = 1.f / s;
#pragma unroll
    for (int i = 0; i < 5; ++i) {
        f32x4 q;
        q[0] = v[4 * i] * inv; q[1] = v[4 * i + 1] * inv;
        q[2] = v[4 * i + 2] * inv; q[3] = v[4 * i + 3] * inv;
        p[i] = q;
    }
}

extern "C" void kernel_launch(void* const* d_in, const int* in_sizes, int n_in,
                              void* d_out, int out_size, void* d_ws, size_t ws_size,
                              hipStream_t stream)
{
    const float* x     = (const float*)d_in[0];
    const float* w     = (const float*)d_in[1];
    const float* mask  = (const float*)d_in[2];
    const float* smask = (const float*)d_in[3];
    float* out = (float*)d_out;

    // workspace (tiny, ~110 KB): fp64 mag^2, index lists, class means
    char* ws = (char*)d_ws;
    double* mag2_ws = (double*)ws;                  // 12000*8 = 96000 B
    int*    idxA    = (int*)(ws + 96000);           // 1488*4
    int*    idxB    = (int*)(ws + 101952);          // 1488*4
    float*  meansA  = (float*)(ws + 107904);        // 320*4

    // output layout (f32 elements), reference return order
    float* score_act = out;                                    // 320
    float* score_bkg = out + 320;                              // 320
    float* featA     = out + 640;                              // 16*93*4096
    float* featB     = featA + (size_t)BB * K_ACT * FF;
    float* features  = featB + (size_t)BB * K_BKG * FF;        // 16*750*4096
    float* cas_buf   = features + (size_t)BB * TT * FF;        // logits then softmax in place

    k_main<<<NROWS / 2, 256, 0, stream>>>(x, w, mask, features, cas_buf, mag2_ws);
    k_mid<<<BB * 3 + BB * CC, 256, 0, stream>>>(mag2_ws, smask, cas_buf, idxA, idxB, meansA);
    k_fin<<<2 * BB * K_ACT + BB, 256, 0, stream>>>(x, cas_buf, meansA, idxA, idxB,
                                                   featA, featB, score_act, score_bkg);
    k_cassm<<<(NROWS + 255) / 256, 256, 0, stream>>>(cas_buf);
}

// Round 3
// 752.475 us; speedup vs baseline: 2.3585x; 2.3585x over previous
//
#include <hip/hip_runtime.h>

#define BB 16
#define TT 750
#define FF 4096
#define CC 20
#define K_ACT 93
#define K_BKG 93
#define NROWS (BB * TT)   // 12000

typedef float f32x4 __attribute__((ext_vector_type(4)));  // NT-builtin-compatible

// ---------------------------------------------------------------------------
// K1: fused features-copy + masked GEMM (cas logits) + ||x||^2 (fp64)
// v3: 2 rows/block (6000 blocks), 256 threads. NO forced waves-per-EU (round 2
// lesson: (256,4) -> 64 VGPR -> catastrophic spills, 10x HBM traffic). Short
// register lifetimes; shfl-butterfly reduction; NT hints on mask/features.
// Optionally (do_sm) also emits the per-row softmax, removing the k_cassm pass.
// ---------------------------------------------------------------------------
__global__ __launch_bounds__(256) void k_main(
    const float* __restrict__ x, const float* __restrict__ w,
    const float* __restrict__ mask, float* __restrict__ features,
    float* __restrict__ cas_raw, float* __restrict__ cas_sm,
    double* __restrict__ mag2_ws, const int do_sm)
{
    const int tid = threadIdx.x;
    const int row0 = blockIdx.x * 2;

    float acc[2][CC];
#pragma unroll
    for (int r = 0; r < 2; ++r)
#pragma unroll
        for (int c = 0; c < CC; ++c) acc[r][c] = 0.f;
    double mg[2] = {0.0, 0.0};

#pragma unroll
    for (int k = 0; k < 2; ++k) {
        const int fb = k * 2048 + tid * 8;
        float mk[2][8];
#pragma unroll
        for (int r = 0; r < 2; ++r) {
            const size_t off = (size_t)(row0 + r) * FF + fb;
            const f32x4 a0 = *(const f32x4*)(x + off);
            const f32x4 a1 = *(const f32x4*)(x + off + 4);
            const f32x4 m0 = __builtin_nontemporal_load((const f32x4*)(mask + off));
            const f32x4 m1 = __builtin_nontemporal_load((const f32x4*)(mask + off + 4));
            __builtin_nontemporal_store(a0, (f32x4*)(features + off));  // pass-through (bit-exact)
            __builtin_nontemporal_store(a1, (f32x4*)(features + off + 4));
            mk[r][0] = a0[0] * m0[0]; mk[r][1] = a0[1] * m0[1];
            mk[r][2] = a0[2] * m0[2]; mk[r][3] = a0[3] * m0[3];
            mk[r][4] = a1[0] * m1[0]; mk[r][5] = a1[1] * m1[1];
            mk[r][6] = a1[2] * m1[2]; mk[r][7] = a1[3] * m1[3];
            mg[r] = fma((double)a0[0], (double)a0[0], mg[r]);
            mg[r] = fma((double)a0[1], (double)a0[1], mg[r]);
            mg[r] = fma((double)a0[2], (double)a0[2], mg[r]);
            mg[r] = fma((double)a0[3], (double)a0[3], mg[r]);
            mg[r] = fma((double)a1[0], (double)a1[0], mg[r]);
            mg[r] = fma((double)a1[1], (double)a1[1], mg[r]);
            mg[r] = fma((double)a1[2], (double)a1[2], mg[r]);
            mg[r] = fma((double)a1[3], (double)a1[3], mg[r]);
            // a0/a1/m0/m1 dead here -> short lifetimes, low pressure
        }
#pragma unroll
        for (int c = 0; c < CC; ++c) {
            const f32x4 w0 = *(const f32x4*)(w + (size_t)c * FF + fb);
            const f32x4 w1 = *(const f32x4*)(w + (size_t)c * FF + fb + 4);
            float wf[8] = {w0[0], w0[1], w0[2], w0[3], w1[0], w1[1], w1[2], w1[3]};
#pragma unroll
            for (int r = 0; r < 2; ++r)
#pragma unroll
                for (int j = 0; j < 8; ++j)
                    acc[r][c] = fmaf(mk[r][j], wf[j], acc[r][c]);
        }
    }

    // 64-lane butterfly reduction; lane 0 of each wave deposits into tiny LDS
    // (static indexing only — never index a register array with a runtime id)
    __shared__ float redw[2][4][CC];
    __shared__ double redd[2][4];
    __shared__ float casrow[2][CC];
    const int wv = tid >> 6;
    const int ln = tid & 63;

#pragma unroll
    for (int r = 0; r < 2; ++r) {
#pragma unroll
        for (int c = 0; c < CC; ++c) {
            float v = acc[r][c];
#pragma unroll
            for (int off = 1; off < 64; off <<= 1) v += __shfl_xor(v, off, 64);
            acc[r][c] = v;
        }
        double d = mg[r];
#pragma unroll
        for (int off = 1; off < 64; off <<= 1) d += __shfl_xor(d, off, 64);
        if (ln == 0) {
#pragma unroll
            for (int c = 0; c < CC; ++c) redw[r][wv][c] = acc[r][c];
            redd[r][wv] = d;
        }
    }
    __syncthreads();
    if (tid < 2 * CC) {
        const int r = tid / CC, c = tid % CC;
        const float s =
            (redw[r][0][c] + redw[r][1][c]) + (redw[r][2][c] + redw[r][3][c]);
        cas_raw[(size_t)(row0 + r) * CC + c] = s;
        casrow[r][c] = s;
    } else if (tid < 2 * CC + 2) {
        const int r = tid - 2 * CC;
        mag2_ws[row0 + r] = (redd[r][0] + redd[r][1]) + (redd[r][2] + redd[r][3]);
    }
    if (do_sm) {
        __syncthreads();
        if (tid < 2) {
            float v[CC];
#pragma unroll
            for (int c = 0; c < CC; ++c) v[c] = casrow[tid][c];
            float m = v[0];
#pragma unroll
            for (int c = 1; c < CC; ++c) m = fmaxf(m, v[c]);
            float s = 0.f;
#pragma unroll
            for (int c = 0; c < CC; ++c) { v[c] = expf(v[c] - m); s += v[c]; }
            const float inv = 1.f / s;
            f32x4* p = (f32x4*)(cas_sm + (size_t)(row0 + tid) * CC);
#pragma unroll
            for (int i = 0; i < 5; ++i) {
                f32x4 q;
                q[0] = v[4 * i] * inv; q[1] = v[4 * i + 1] * inv;
                q[2] = v[4 * i + 2] * inv; q[3] = v[4 * i + 3] * inv;
                p[i] = q;
            }
        }
    }
}

// ---------------------------------------------------------------------------
// K2 (merged): blocks [0,48) = exact top-k index selection
//              blocks [48,368) = mean of top-93 of each cas column
// ---------------------------------------------------------------------------
__global__ __launch_bounds__(256) void k_mid(
    const double* __restrict__ mag2_ws, const float* __restrict__ smask,
    const float* __restrict__ cas_ws,
    int* __restrict__ idxA, int* __restrict__ idxB, float* __restrict__ meansA)
{
    const int bid = blockIdx.x;
    const int tid = threadIdx.x;

    if (bid < BB * 3) {
        // ---- top-k body (stable desc, lower index first; fp64 keys) ----
        const int b = bid / 3;
        const int chunk = bid % 3;

        __shared__ double m2[TT];
        __shared__ unsigned char alive[TT];
        __shared__ double mred[256];

        for (int t = tid; t < TT; t += 256) {
            m2[t] = mag2_ws[b * TT + t];
            alive[t] = (smask[b * TT + t] != 0.f);
        }
        __syncthreads();
        double lm = 0.0;
        for (int t = tid; t < TT; t += 256) lm = fmax(lm, m2[t]);
        mred[tid] = lm;
        __syncthreads();
        for (int s = 128; s > 0; s >>= 1) {
            if (tid < s) mred[tid] = fmax(mred[tid], mred[tid + s]);
            __syncthreads();
        }
        const double mx = mred[0];

        const int t = chunk * 250 + tid;
        if (tid < 250 && t < TT && alive[t]) {
            const double v = m2[t];
            const bool posB = v < mx;  // bkg key (mx - v)*s is positive
            int rA = 0, rB = 0;
            for (int u = 0; u < TT; ++u) {
                if (!alive[u]) continue;
                const double wv = m2[u];
                if (wv > v || (wv == v && u < t)) ++rA;
                if (posB && wv < mx && (wv < v || (wv == v && u < t))) ++rB;
            }
            if (rA < K_ACT) idxA[b * K_ACT + rA] = t;
            if (posB && rB < K_BKG) idxB[b * K_BKG + rB] = t;
        }
    } else {
        // ---- colmean body ----
        const int cb = bid - BB * 3;
        const int b = cb / CC;
        const int c = cb % CC;

        __shared__ float col[TT];
        __shared__ float pred[256];

        for (int t = tid; t < TT; t += 256) col[t] = cas_ws[(size_t)(b * TT + t) * CC + c];
        __syncthreads();

        float loc = 0.f;
        for (int t = tid; t < TT; t += 256) {
            const float v = col[t];
            int cnt = 0;
            for (int u = 0; u < TT; ++u) {
                const float wv = col[u];
                cnt += (wv > v) || (wv == v && u < t);
            }
            if (cnt < K_ACT) loc += v;
        }
        pred[tid] = loc;
        __syncthreads();
        for (int s = 128; s > 0; s >>= 1) {
            if (tid < s) pred[tid] += pred[tid + s];
            __syncthreads();
        }
        if (tid == 0) meansA[b * CC + c] = pred[0] / (float)K_ACT;
    }
}

// ---------------------------------------------------------------------------
// K3 (merged): blocks [0,2976) = gather feat_act / feat_bkg rows (NT stores)
//              blocks [2976,2992) = score_bkg mean + both softmaxes
// ---------------------------------------------------------------------------
__global__ __launch_bounds__(256) void k_fin(
    const float* __restrict__ x, const float* __restrict__ cas_ws,
    const float* __restrict__ meansA,
    const int* __restrict__ idxA, const int* __restrict__ idxB,
    float* __restrict__ featA, float* __restrict__ featB,
    float* __restrict__ score_act, float* __restrict__ score_bkg)
{
    int g = blockIdx.x;
    const int tid = threadIdx.x;
    const int nA = BB * K_ACT;

    if (g < 2 * nA) {
        // ---- gather body ----
        const bool isB = (g >= nA);
        if (isB) g -= nA;
        const int b = g / K_ACT;
        int t = (isB ? idxB : idxA)[g];
        t = min(max(t, 0), TT - 1);
        const f32x4* src = (const f32x4*)(x + (size_t)(b * TT + t) * FF);
        f32x4* dst = (f32x4*)((isB ? featB : featA) + (size_t)g * FF);
        for (int i = tid; i < FF / 4; i += 256)
            __builtin_nontemporal_store(src[i], dst + i);
    } else {
        // ---- scores body ----
        const int b = g - 2 * nA;
        __shared__ float mB[CC];

        if (tid < CC) {
            float s = 0.f;
            for (int j = 0; j < K_BKG; ++j) {
                int t = idxB[b * K_BKG + j];
                t = min(max(t, 0), TT - 1);
                s += cas_ws[(size_t)(b * TT + t) * CC + tid];
            }
            mB[tid] = s / (float)K_BKG;
        }
        __syncthreads();
        if (tid == 0) {
            float va[CC], vb[CC];
            float ma = -1e30f, sa = 0.f;
            for (int c = 0; c < CC; ++c) { va[c] = meansA[b * CC + c]; ma = fmaxf(ma, va[c]); }
            for (int c = 0; c < CC; ++c) { va[c] = expf(va[c] - ma); sa += va[c]; }
            for (int c = 0; c < CC; ++c) score_act[b * CC + c] = va[c] / sa;
            float mb = -1e30f, sb = 0.f;
            for (int c = 0; c < CC; ++c) { vb[c] = mB[c]; mb = fmaxf(mb, vb[c]); }
            for (int c = 0; c < CC; ++c) { vb[c] = expf(vb[c] - mb); sb += vb[c]; }
            for (int c = 0; c < CC; ++c) score_bkg[b * CC + c] = vb[c] / sb;
        }
    }
}

// ---------------------------------------------------------------------------
// K4 (fallback only, when workspace can't hold raw logits): in-place softmax
// ---------------------------------------------------------------------------
__global__ __launch_bounds__(256) void k_cassm(float* __restrict__ cas)
{
    const int row = blockIdx.x * 256 + threadIdx.x;
    if (row >= NROWS) return;
    f32x4* p = (f32x4*)(cas + (size_t)row * CC);
    float v[CC];
#pragma unroll
    for (int i = 0; i < 5; ++i) {
        const f32x4 q = p[i];
        v[4 * i] = q[0]; v[4 * i + 1] = q[1]; v[4 * i + 2] = q[2]; v[4 * i + 3] = q[3];
    }
    float m = v[0];
#pragma unroll
    for (int c = 1; c < CC; ++c) m = fmaxf(m, v[c]);
    float s = 0.f;
#pragma unroll
    for (int c = 0; c < CC; ++c) { v[c] = expf(v[c] - m); s += v[c]; }
    const float inv = 1.f / s;
#pragma unroll
    for (int i = 0; i < 5; ++i) {
        f32x4 q;
        q[0] = v[4 * i] * inv; q[1] = v[4 * i + 1] * inv;
        q[2] = v[4 * i + 2] * inv; q[3] = v[4 * i + 3] * inv;
        p[i] = q;
    }
}

extern "C" void kernel_launch(void* const* d_in, const int* in_sizes, int n_in,
                              void* d_out, int out_size, void* d_ws, size_t ws_size,
                              hipStream_t stream)
{
    const float* x     = (const float*)d_in[0];
    const float* w     = (const float*)d_in[1];
    const float* mask  = (const float*)d_in[2];
    const float* smask = (const float*)d_in[3];
    float* out = (float*)d_out;

    // workspace layout
    char* ws = (char*)d_ws;
    double* mag2_ws = (double*)ws;                  // 12000*8 = 96000 B
    int*    idxA    = (int*)(ws + 96000);           // 1488*4
    int*    idxB    = (int*)(ws + 101952);          // 1488*4
    float*  meansA  = (float*)(ws + 107904);        // 320*4 -> 109184
    float*  casraw_ws = (float*)(ws + 109568);      // optional: 12000*20*4 = 960000 B
    const size_t WS_NEED = 109568 + 960000;

    // output layout (f32 elements), reference return order
    float* score_act = out;                                    // 320
    float* score_bkg = out + 320;                              // 320
    float* featA     = out + 640;                              // 16*93*4096
    float* featB     = featA + (size_t)BB * K_ACT * FF;
    float* features  = featB + (size_t)BB * K_BKG * FF;        // 16*750*4096
    float* cas_out   = features + (size_t)BB * TT * FF;        // 16*750*20

    const bool big_ws = (ws_size >= WS_NEED);
    float* cas_raw = big_ws ? casraw_ws : cas_out;   // raw logits live here

    k_main<<<NROWS / 2, 256, 0, stream>>>(x, w, mask, features, cas_raw, cas_out,
                                          mag2_ws, big_ws ? 1 : 0);
    k_mid<<<BB * 3 + BB * CC, 256, 0, stream>>>(mag2_ws, smask, cas_raw, idxA, idxB, meansA);
    k_fin<<<2 * BB * K_ACT + BB, 256, 0, stream>>>(x, cas_raw, meansA, idxA, idxB,
                                                   featA, featB, score_act, score_bkg);
    if (!big_ws)
        k_cassm<<<(NROWS + 255) / 256, 256, 0, stream>>>(cas_out);
}

// Round 4
// 648.783 us; speedup vs baseline: 2.7354x; 1.1598x over previous
//
#include <hip/hip_runtime.h>

#define BB 16
#define TT 750
#define FF 4096
#define CC 20
#define K_ACT 93
#define K_BKG 93
#define NROWS (BB * TT)   // 12000

typedef float f32x4 __attribute__((ext_vector_type(4)));  // NT-builtin-compatible

// ---------------------------------------------------------------------------
// K1: fused features-copy + masked GEMM (cas logits) + ||x||^2 (fp64)
// v4: identical arithmetic to v3 (same element mapping, same FMA order), but
//  - k-loop NOT unrolled (#pragma unroll 1): only one 2048-chunk live at a
//    time -> natural live set ~100 VGPR (v3's full unroll hoisted to 212)
//  - __launch_bounds__(256,3): cap ~170 VGPR, 3 waves/SIMD. NOT (256,4):
//    that forced 64 VGPR and catastrophic spills in v2 (10x HBM traffic).
// ---------------------------------------------------------------------------
__global__ __launch_bounds__(256, 3) void k_main(
    const float* __restrict__ x, const float* __restrict__ w,
    const float* __restrict__ mask, float* __restrict__ features,
    float* __restrict__ cas_raw, float* __restrict__ cas_sm,
    double* __restrict__ mag2_ws, const int do_sm)
{
    const int tid = threadIdx.x;
    const int row0 = blockIdx.x * 2;

    float acc[2][CC];
#pragma unroll
    for (int r = 0; r < 2; ++r)
#pragma unroll
        for (int c = 0; c < CC; ++c) acc[r][c] = 0.f;
    double mg[2] = {0.0, 0.0};

#pragma unroll 1
    for (int k = 0; k < 2; ++k) {
        const int fb = k * 2048 + tid * 8;
        float mk[2][8];
#pragma unroll
        for (int r = 0; r < 2; ++r) {
            const size_t off = (size_t)(row0 + r) * FF + fb;
            const f32x4 a0 = *(const f32x4*)(x + off);
            const f32x4 a1 = *(const f32x4*)(x + off + 4);
            const f32x4 m0 = __builtin_nontemporal_load((const f32x4*)(mask + off));
            const f32x4 m1 = __builtin_nontemporal_load((const f32x4*)(mask + off + 4));
            __builtin_nontemporal_store(a0, (f32x4*)(features + off));  // pass-through (bit-exact)
            __builtin_nontemporal_store(a1, (f32x4*)(features + off + 4));
            mk[r][0] = a0[0] * m0[0]; mk[r][1] = a0[1] * m0[1];
            mk[r][2] = a0[2] * m0[2]; mk[r][3] = a0[3] * m0[3];
            mk[r][4] = a1[0] * m1[0]; mk[r][5] = a1[1] * m1[1];
            mk[r][6] = a1[2] * m1[2]; mk[r][7] = a1[3] * m1[3];
            mg[r] = fma((double)a0[0], (double)a0[0], mg[r]);
            mg[r] = fma((double)a0[1], (double)a0[1], mg[r]);
            mg[r] = fma((double)a0[2], (double)a0[2], mg[r]);
            mg[r] = fma((double)a0[3], (double)a0[3], mg[r]);
            mg[r] = fma((double)a1[0], (double)a1[0], mg[r]);
            mg[r] = fma((double)a1[1], (double)a1[1], mg[r]);
            mg[r] = fma((double)a1[2], (double)a1[2], mg[r]);
            mg[r] = fma((double)a1[3], (double)a1[3], mg[r]);
            // a0/a1/m0/m1 dead here -> short lifetimes, low pressure
        }
#pragma unroll
        for (int c = 0; c < CC; ++c) {
            const f32x4 w0 = *(const f32x4*)(w + (size_t)c * FF + fb);
            const f32x4 w1 = *(const f32x4*)(w + (size_t)c * FF + fb + 4);
            float wf[8] = {w0[0], w0[1], w0[2], w0[3], w1[0], w1[1], w1[2], w1[3]};
#pragma unroll
            for (int r = 0; r < 2; ++r)
#pragma unroll
                for (int j = 0; j < 8; ++j)
                    acc[r][c] = fmaf(mk[r][j], wf[j], acc[r][c]);
        }
    }

    // 64-lane butterfly reduction; lane 0 of each wave deposits into tiny LDS
    // (static indexing only — never index a register array with a runtime id)
    __shared__ float redw[2][4][CC];
    __shared__ double redd[2][4];
    __shared__ float casrow[2][CC];
    const int wv = tid >> 6;
    const int ln = tid & 63;

#pragma unroll
    for (int r = 0; r < 2; ++r) {
#pragma unroll
        for (int c = 0; c < CC; ++c) {
            float v = acc[r][c];
#pragma unroll
            for (int off = 1; off < 64; off <<= 1) v += __shfl_xor(v, off, 64);
            acc[r][c] = v;
        }
        double d = mg[r];
#pragma unroll
        for (int off = 1; off < 64; off <<= 1) d += __shfl_xor(d, off, 64);
        if (ln == 0) {
#pragma unroll
            for (int c = 0; c < CC; ++c) redw[r][wv][c] = acc[r][c];
            redd[r][wv] = d;
        }
    }
    __syncthreads();
    if (tid < 2 * CC) {
        const int r = tid / CC, c = tid % CC;
        const float s =
            (redw[r][0][c] + redw[r][1][c]) + (redw[r][2][c] + redw[r][3][c]);
        cas_raw[(size_t)(row0 + r) * CC + c] = s;
        casrow[r][c] = s;
    } else if (tid < 2 * CC + 2) {
        const int r = tid - 2 * CC;
        mag2_ws[row0 + r] = (redd[r][0] + redd[r][1]) + (redd[r][2] + redd[r][3]);
    }
    if (do_sm) {
        __syncthreads();
        if (tid < 2) {
            float v[CC];
#pragma unroll
            for (int c = 0; c < CC; ++c) v[c] = casrow[tid][c];
            float m = v[0];
#pragma unroll
            for (int c = 1; c < CC; ++c) m = fmaxf(m, v[c]);
            float s = 0.f;
#pragma unroll
            for (int c = 0; c < CC; ++c) { v[c] = expf(v[c] - m); s += v[c]; }
            const float inv = 1.f / s;
            f32x4* p = (f32x4*)(cas_sm + (size_t)(row0 + tid) * CC);
#pragma unroll
            for (int i = 0; i < 5; ++i) {
                f32x4 q;
                q[0] = v[4 * i] * inv; q[1] = v[4 * i + 1] * inv;
                q[2] = v[4 * i + 2] * inv; q[3] = v[4 * i + 3] * inv;
                p[i] = q;
            }
        }
    }
}

// ---------------------------------------------------------------------------
// K2 (merged): blocks [0,48) = exact top-k index selection
//              blocks [48,368) = mean of top-93 of each cas column
// ---------------------------------------------------------------------------
__global__ __launch_bounds__(256) void k_mid(
    const double* __restrict__ mag2_ws, const float* __restrict__ smask,
    const float* __restrict__ cas_ws,
    int* __restrict__ idxA, int* __restrict__ idxB, float* __restrict__ meansA)
{
    const int bid = blockIdx.x;
    const int tid = threadIdx.x;

    if (bid < BB * 3) {
        // ---- top-k body (stable desc, lower index first; fp64 keys) ----
        const int b = bid / 3;
        const int chunk = bid % 3;

        __shared__ double m2[TT];
        __shared__ unsigned char alive[TT];
        __shared__ double mred[256];

        for (int t = tid; t < TT; t += 256) {
            m2[t] = mag2_ws[b * TT + t];
            alive[t] = (smask[b * TT + t] != 0.f);
        }
        __syncthreads();
        double lm = 0.0;
        for (int t = tid; t < TT; t += 256) lm = fmax(lm, m2[t]);
        mred[tid] = lm;
        __syncthreads();
        for (int s = 128; s > 0; s >>= 1) {
            if (tid < s) mred[tid] = fmax(mred[tid], mred[tid + s]);
            __syncthreads();
        }
        const double mx = mred[0];

        const int t = chunk * 250 + tid;
        if (tid < 250 && t < TT && alive[t]) {
            const double v = m2[t];
            const bool posB = v < mx;  // bkg key (mx - v)*s is positive
            int rA = 0, rB = 0;
            for (int u = 0; u < TT; ++u) {
                if (!alive[u]) continue;
                const double wv = m2[u];
                if (wv > v || (wv == v && u < t)) ++rA;
                if (posB && wv < mx && (wv < v || (wv == v && u < t))) ++rB;
            }
            if (rA < K_ACT) idxA[b * K_ACT + rA] = t;
            if (posB && rB < K_BKG) idxB[b * K_BKG + rB] = t;
        }
    } else {
        // ---- colmean body ----
        const int cb = bid - BB * 3;
        const int b = cb / CC;
        const int c = cb % CC;

        __shared__ float col[TT];
        __shared__ float pred[256];

        for (int t = tid; t < TT; t += 256) col[t] = cas_ws[(size_t)(b * TT + t) * CC + c];
        __syncthreads();

        float loc = 0.f;
        for (int t = tid; t < TT; t += 256) {
            const float v = col[t];
            int cnt = 0;
            for (int u = 0; u < TT; ++u) {
                const float wv = col[u];
                cnt += (wv > v) || (wv == v && u < t);
            }
            if (cnt < K_ACT) loc += v;
        }
        pred[tid] = loc;
        __syncthreads();
        for (int s = 128; s > 0; s >>= 1) {
            if (tid < s) pred[tid] += pred[tid + s];
            __syncthreads();
        }
        if (tid == 0) meansA[b * CC + c] = pred[0] / (float)K_ACT;
    }
}

// ---------------------------------------------------------------------------
// K3 (merged): blocks [0,2976) = gather feat_act / feat_bkg rows (NT stores)
//              blocks [2976,2992) = score_bkg mean + both softmaxes
// ---------------------------------------------------------------------------
__global__ __launch_bounds__(256) void k_fin(
    const float* __restrict__ x, const float* __restrict__ cas_ws,
    const float* __restrict__ meansA,
    const int* __restrict__ idxA, const int* __restrict__ idxB,
    float* __restrict__ featA, float* __restrict__ featB,
    float* __restrict__ score_act, float* __restrict__ score_bkg)
{
    int g = blockIdx.x;
    const int tid = threadIdx.x;
    const int nA = BB * K_ACT;

    if (g < 2 * nA) {
        // ---- gather body ----
        const bool isB = (g >= nA);
        if (isB) g -= nA;
        const int b = g / K_ACT;
        int t = (isB ? idxB : idxA)[g];
        t = min(max(t, 0), TT - 1);
        const f32x4* src = (const f32x4*)(x + (size_t)(b * TT + t) * FF);
        f32x4* dst = (f32x4*)((isB ? featB : featA) + (size_t)g * FF);
        for (int i = tid; i < FF / 4; i += 256)
            __builtin_nontemporal_store(src[i], dst + i);
    } else {
        // ---- scores body ----
        const int b = g - 2 * nA;
        __shared__ float mB[CC];

        if (tid < CC) {
            float s = 0.f;
            for (int j = 0; j < K_BKG; ++j) {
                int t = idxB[b * K_BKG + j];
                t = min(max(t, 0), TT - 1);
                s += cas_ws[(size_t)(b * TT + t) * CC + tid];
            }
            mB[tid] = s / (float)K_BKG;
        }
        __syncthreads();
        if (tid == 0) {
            float va[CC], vb[CC];
            float ma = -1e30f, sa = 0.f;
            for (int c = 0; c < CC; ++c) { va[c] = meansA[b * CC + c]; ma = fmaxf(ma, va[c]); }
            for (int c = 0; c < CC; ++c) { va[c] = expf(va[c] - ma); sa += va[c]; }
            for (int c = 0; c < CC; ++c) score_act[b * CC + c] = va[c] / sa;
            float mb = -1e30f, sb = 0.f;
            for (int c = 0; c < CC; ++c) { vb[c] = mB[c]; mb = fmaxf(mb, vb[c]); }
            for (int c = 0; c < CC; ++c) { vb[c] = expf(vb[c] - mb); sb += vb[c]; }
            for (int c = 0; c < CC; ++c) score_bkg[b * CC + c] = vb[c] / sb;
        }
    }
}

// ---------------------------------------------------------------------------
// K4 (fallback only, when workspace can't hold raw logits): in-place softmax
// ---------------------------------------------------------------------------
__global__ __launch_bounds__(256) void k_cassm(float* __restrict__ cas)
{
    const int row = blockIdx.x * 256 + threadIdx.x;
    if (row >= NROWS) return;
    f32x4* p = (f32x4*)(cas + (size_t)row * CC);
    float v[CC];
#pragma unroll
    for (int i = 0; i < 5; ++i) {
        const f32x4 q = p[i];
        v[4 * i] = q[0]; v[4 * i + 1] = q[1]; v[4 * i + 2] = q[2]; v[4 * i + 3] = q[3];
    }
    float m = v[0];
#pragma unroll
    for (int c = 1; c < CC; ++c) m = fmaxf(m, v[c]);
    float s = 0.f;
#pragma unroll
    for (int c = 0; c < CC; ++c) { v[c] = expf(v[c] - m); s += v[c]; }
    const float inv = 1.f / s;
#pragma unroll
    for (int i = 0; i < 5; ++i) {
        f32x4 q;
        q[0] = v[4 * i] * inv; q[1] = v[4 * i + 1] * inv;
        q[2] = v[4 * i + 2] * inv; q[3] = v[4 * i + 3] * inv;
        p[i] = q;
    }
}

extern "C" void kernel_launch(void* const* d_in, const int* in_sizes, int n_in,
                              void* d_out, int out_size, void* d_ws, size_t ws_size,
                              hipStream_t stream)
{
    const float* x     = (const float*)d_in[0];
    const float* w     = (const float*)d_in[1];
    const float* mask  = (const float*)d_in[2];
    const float* smask = (const float*)d_in[3];
    float* out = (float*)d_out;

    // workspace layout
    char* ws = (char*)d_ws;
    double* mag2_ws = (double*)ws;                  // 12000*8 = 96000 B
    int*    idxA    = (int*)(ws + 96000);           // 1488*4
    int*    idxB    = (int*)(ws + 101952);          // 1488*4
    float*  meansA  = (float*)(ws + 107904);        // 320*4 -> 109184
    float*  casraw_ws = (float*)(ws + 109568);      // optional: 12000*20*4 = 960000 B
    const size_t WS_NEED = 109568 + 960000;

    // output layout (f32 elements), reference return order
    float* score_act = out;                                    // 320
    float* score_bkg = out + 320;                              // 320
    float* featA     = out + 640;                              // 16*93*4096
    float* featB     = featA + (size_t)BB * K_ACT * FF;
    float* features  = featB + (size_t)BB * K_BKG * FF;        // 16*750*4096
    float* cas_out   = features + (size_t)BB * TT * FF;        // 16*750*20

    const bool big_ws = (ws_size >= WS_NEED);
    float* cas_raw = big_ws ? casraw_ws : cas_out;   // raw logits live here

    k_main<<<NROWS / 2, 256, 0, stream>>>(x, w, mask, features, cas_raw, cas_out,
                                          mag2_ws, big_ws ? 1 : 0);
    k_mid<<<BB * 3 + BB * CC, 256, 0, stream>>>(mag2_ws, smask, cas_raw, idxA, idxB, meansA);
    k_fin<<<2 * BB * K_ACT + BB, 256, 0, stream>>>(x, cas_raw, meansA, idxA, idxB,
                                                   featA, featB, score_act, score_bkg);
    if (!big_ws)
        k_cassm<<<(NROWS + 255) / 256, 256, 0, stream>>>(cas_out);
}